// Round 1
// baseline (77.527 us; speedup 1.0000x reference)
//
#include <hip/hip_runtime.h>

// SuperResolution degradation: per-sample block-mean over 2^t x 2^t blocks,
// broadcast back over the block (== avg_pool(k=2^t) + nearest upsample).
// x0: [256,3,256,256] f32, t: [256] int (0..3). Output same shape as x0.
//
// Layout strategy (memory-bound, target HBM BW roofline):
//  - grid: one workgroup per 32x256 chunk of a (b,c) plane -> t[b] is
//    workgroup-uniform, branch on k is non-divergent.
//  - 256 threads/block: wave w (tid>>6) owns rows [w*8, w*8+8), lane l owns
//    cols [4l, 4l+4). Each thread: 8 float4 loads + 8 float4 stores
//    (global_load/store_dwordx4, fully coalesced).
//  - k=1: copy. k=2: 2x2 block fully in-thread. k=4: 4x4 fully in-thread.
//    k=8: 8 cols span lanes (l, l^1) -> one __shfl_xor. No LDS.

#define W 256
#define CHN 3
#define BATCH 256
#define CHUNKS_PER_PLANE 8            // 256 rows / 32 rows per chunk
#define CHUNK_FLOATS 8192             // 32*256

__global__ __launch_bounds__(256)
void sr_degrade_kernel(const float* __restrict__ x,
                       const int* __restrict__ t,
                       float* __restrict__ out) {
    const int ch   = blockIdx.x;                  // 0 .. B*C*8-1
    const int b    = ch / (CHN * CHUNKS_PER_PLANE);
    const int tid  = threadIdx.x;
    const int lane = tid & 63;
    const int wave = tid >> 6;

    // chunk base: chunks tile the tensor contiguously (8192 floats each)
    const long long base = (long long)ch * CHUNK_FLOATS
                         + (long long)wave * 8 * W   // row base within chunk
                         + lane * 4;                 // col base
    const float* __restrict__ src = x + base;
    float*       __restrict__ dst = out + base;

    const int tv = t[b];   // workgroup-uniform: 0..3

    float4 v[8];
    #pragma unroll
    for (int r = 0; r < 8; ++r)
        v[r] = *reinterpret_cast<const float4*>(src + r * W);

    if (tv == 0) {
        #pragma unroll
        for (int r = 0; r < 8; ++r)
            *reinterpret_cast<float4*>(dst + r * W) = v[r];
        return;
    }
    if (tv == 1) {
        // k=2: row pairs (2rp,2rp+1) x col pairs (x,y) and (z,w)
        #pragma unroll
        for (int rp = 0; rp < 4; ++rp) {
            const float4 a = v[2 * rp];
            const float4 c = v[2 * rp + 1];
            const float m0 = (a.x + a.y + c.x + c.y) * 0.25f;
            const float m1 = (a.z + a.w + c.z + c.w) * 0.25f;
            const float4 o = make_float4(m0, m0, m1, m1);
            *reinterpret_cast<float4*>(dst + (2 * rp)     * W) = o;
            *reinterpret_cast<float4*>(dst + (2 * rp + 1) * W) = o;
        }
        return;
    }
    if (tv == 2) {
        // k=4: two 4x4 blocks (rows 0-3, rows 4-7), cols = this thread's 4
        #pragma unroll
        for (int h = 0; h < 2; ++h) {
            float s = 0.0f;
            #pragma unroll
            for (int r = 0; r < 4; ++r) {
                const float4 a = v[4 * h + r];
                s += (a.x + a.y) + (a.z + a.w);
            }
            const float m = s * (1.0f / 16.0f);
            const float4 o = make_float4(m, m, m, m);
            #pragma unroll
            for (int r = 0; r < 4; ++r)
                *reinterpret_cast<float4*>(dst + (4 * h + r) * W) = o;
        }
        return;
    }
    // tv == 3, k=8: all 8 rows in-thread; 8 cols span lanes (l, l^1)
    {
        float s = 0.0f;
        #pragma unroll
        for (int r = 0; r < 8; ++r) {
            const float4 a = v[r];
            s += (a.x + a.y) + (a.z + a.w);
        }
        s += __shfl_xor(s, 1);
        const float m = s * (1.0f / 64.0f);
        const float4 o = make_float4(m, m, m, m);
        #pragma unroll
        for (int r = 0; r < 8; ++r)
            *reinterpret_cast<float4*>(dst + r * W) = o;
    }
}

extern "C" void kernel_launch(void* const* d_in, const int* in_sizes, int n_in,
                              void* d_out, int out_size, void* d_ws, size_t ws_size,
                              hipStream_t stream) {
    const float* x = (const float*)d_in[0];
    const int*   t = (const int*)d_in[1];
    float* out = (float*)d_out;

    const int nblocks = BATCH * CHN * CHUNKS_PER_PLANE;  // 6144
    sr_degrade_kernel<<<nblocks, 256, 0, stream>>>(x, t, out);
}

// Round 3
// 63.024 us; speedup vs baseline: 1.2301x; 1.2301x over previous
//
#include <hip/hip_runtime.h>

// SuperResolution degradation: per-sample block-mean over 2^t x 2^t blocks,
// broadcast back over the block (== avg_pool(k=2^t) + nearest upsample).
// x0: [256,3,256,256] f32, t: [256] int (0..3). Output same shape as x0.
//
// R3 = R2 with the compile fix: __builtin_nontemporal_store needs a native
// clang vector type, not HIP_vector_type<float,4>. Use ext_vector_type(4).
//
// Rationale: output is write-once/never-read -> nontemporal stores keep the
// 201 MB output stream from evicting the 201 MB input out of the 256 MB L3.
// Input stays L3-resident across graph replays; HBM sees ~write-only traffic
// (memset calibration from R1 counters: ~7 TB/s, 87-89% of peak).
//
// Layout (unchanged):
//  - one workgroup per 32x256 chunk of a (b,c) plane -> t[b] workgroup-uniform
//  - wave w owns rows [w*8, w*8+8), lane l owns cols [4l, 4l+4)
//  - 8x dwordx4 loads + 8x dwordx4 nt-stores per thread, fully coalesced
//  - k=1 copy; k=2,4 in-thread block mean; k=8 one __shfl_xor(s,1). No LDS.

#define W 256
#define CHN 3
#define BATCH 256
#define CHUNKS_PER_PLANE 8            // 256 rows / 32 rows per chunk
#define CHUNK_FLOATS 8192             // 32*256

typedef float f32x4 __attribute__((ext_vector_type(4)));

__device__ __forceinline__ void nt_store4(float* p, float a, float b, float c, float d) {
    f32x4 v = {a, b, c, d};
    __builtin_nontemporal_store(v, reinterpret_cast<f32x4*>(p));
}

__global__ __launch_bounds__(256)
void sr_degrade_kernel(const float* __restrict__ x,
                       const int* __restrict__ t,
                       float* __restrict__ out) {
    const int ch   = blockIdx.x;                  // 0 .. B*C*8-1
    const int b    = ch / (CHN * CHUNKS_PER_PLANE);
    const int tid  = threadIdx.x;
    const int lane = tid & 63;
    const int wave = tid >> 6;

    const long long base = (long long)ch * CHUNK_FLOATS
                         + (long long)wave * 8 * W   // row base within chunk
                         + lane * 4;                 // col base
    const float* __restrict__ src = x + base;
    float*       __restrict__ dst = out + base;

    const int tv = t[b];   // workgroup-uniform: 0..3

    f32x4 v[8];
    #pragma unroll
    for (int r = 0; r < 8; ++r)
        v[r] = *reinterpret_cast<const f32x4*>(src + r * W);

    if (tv == 0) {
        #pragma unroll
        for (int r = 0; r < 8; ++r)
            __builtin_nontemporal_store(v[r], reinterpret_cast<f32x4*>(dst + r * W));
        return;
    }
    if (tv == 1) {
        // k=2: row pairs (2rp,2rp+1) x col pairs (x,y) and (z,w)
        #pragma unroll
        for (int rp = 0; rp < 4; ++rp) {
            const f32x4 a = v[2 * rp];
            const f32x4 c = v[2 * rp + 1];
            const float m0 = (a.x + a.y + c.x + c.y) * 0.25f;
            const float m1 = (a.z + a.w + c.z + c.w) * 0.25f;
            nt_store4(dst + (2 * rp)     * W, m0, m0, m1, m1);
            nt_store4(dst + (2 * rp + 1) * W, m0, m0, m1, m1);
        }
        return;
    }
    if (tv == 2) {
        // k=4: two 4x4 blocks (rows 0-3, rows 4-7), cols = this thread's 4
        #pragma unroll
        for (int h = 0; h < 2; ++h) {
            float s = 0.0f;
            #pragma unroll
            for (int r = 0; r < 4; ++r) {
                const f32x4 a = v[4 * h + r];
                s += (a.x + a.y) + (a.z + a.w);
            }
            const float m = s * (1.0f / 16.0f);
            #pragma unroll
            for (int r = 0; r < 4; ++r)
                nt_store4(dst + (4 * h + r) * W, m, m, m, m);
        }
        return;
    }
    // tv == 3, k=8: all 8 rows in-thread; 8 cols span lanes (l, l^1)
    {
        float s = 0.0f;
        #pragma unroll
        for (int r = 0; r < 8; ++r) {
            const f32x4 a = v[r];
            s += (a.x + a.y) + (a.z + a.w);
        }
        s += __shfl_xor(s, 1);
        const float m = s * (1.0f / 64.0f);
        #pragma unroll
        for (int r = 0; r < 8; ++r)
            nt_store4(dst + r * W, m, m, m, m);
    }
}

extern "C" void kernel_launch(void* const* d_in, const int* in_sizes, int n_in,
                              void* d_out, int out_size, void* d_ws, size_t ws_size,
                              hipStream_t stream) {
    const float* x = (const float*)d_in[0];
    const int*   t = (const int*)d_in[1];
    float* out = (float*)d_out;

    const int nblocks = BATCH * CHN * CHUNKS_PER_PLANE;  // 6144
    sr_degrade_kernel<<<nblocks, 256, 0, stream>>>(x, t, out);
}